// Round 3
// baseline (375.793 us; speedup 1.0000x reference)
//
#include <hip/hip_runtime.h>
#include <math.h>

#define NL 16
#define TS (1u << 19)
#define TMASK (TS - 1u)
#define PRIME 2654435761u

struct ScalePack { float s[NL]; };

__global__ __launch_bounds__(256)
void hashgrid2d_fwd(const float2* __restrict__ x,     // N float2 (px, py), fp32
                    const float2* __restrict__ feat,  // [g][l][TS] float2, fp32
                    const int* __restrict__ hidx,     // N int32
                    float4* __restrict__ out,         // N*8 float4 = N*32 fp32
                    ScalePack sp, int N)
{
    int n = blockIdx.x * blockDim.x + threadIdx.x;
    if (n >= N) return;

    float2 p = x[n];
    float px = p.x, py = p.y;
    int g = hidx[n];
    const float2* fb = feat + (size_t)g * ((size_t)NL * TS);

    float of[2 * NL];

    #pragma unroll 4
    for (int l = 0; l < NL; ++l) {
        float s  = sp.s[l];
        float fx = px * s;
        float fy = py * s;
        float fx0 = floorf(fx), fy0 = floorf(fy);
        float wx = fx - fx0, wy = fy - fy0;
        unsigned ix = (unsigned)(int)fx0;
        unsigned iy = (unsigned)(int)fy0;
        unsigned hy0 = iy * PRIME;
        unsigned hy1 = (iy + 1u) * PRIME;

        const float2* tab = fb + (size_t)l * TS;
        float2 c00 = tab[( ix       ^ hy0) & TMASK];
        float2 c10 = tab[((ix + 1u) ^ hy0) & TMASK];
        float2 c01 = tab[( ix       ^ hy1) & TMASK];
        float2 c11 = tab[((ix + 1u) ^ hy1) & TMASK];

        float w00 = (1.f - wx) * (1.f - wy);
        float w10 = wx * (1.f - wy);
        float w01 = (1.f - wx) * wy;
        float w11 = wx * wy;

        of[2 * l]     = w00 * c00.x + w10 * c10.x + w01 * c01.x + w11 * c11.x;
        of[2 * l + 1] = w00 * c00.y + w10 * c10.y + w01 * c01.y + w11 * c11.y;
    }

    float4* op = out + (size_t)n * 8;
    #pragma unroll
    for (int q = 0; q < 8; ++q)
        op[q] = make_float4(of[4 * q], of[4 * q + 1], of[4 * q + 2], of[4 * q + 3]);
}

extern "C" void kernel_launch(void* const* d_in, const int* in_sizes, int n_in,
                              void* d_out, int out_size, void* d_ws, size_t ws_size,
                              hipStream_t stream) {
    const float2* x    = (const float2*)d_in[0];   // fp32, (N,2)
    const float2* feat = (const float2*)d_in[1];   // fp32, (2,16,T,2)
    const int*    hidx = (const int*)d_in[2];      // int32, (N,1)
    int N = in_sizes[0] / 2;

    // Replicate reference _resolutions() exactly: same double-precision
    // log/exp/pow sequence as CPython's math module (same libm), then
    // truncating int(). Levels 3,6,9,12,15 sit 1 ulp from exact powers of
    // two — do not hardcode.
    ScalePack sp;
    double b = exp((log(512.0) - log(16.0)) / 15.0);
    for (int i = 0; i < NL; ++i) {
        int r = (int)(16.0 * pow(b, (double)i));
        sp.s[i] = (float)(r - 1);
    }

    int threads = 256;
    int blocks = (N + threads - 1) / threads;
    hipLaunchKernelGGL(hashgrid2d_fwd, dim3(blocks), dim3(threads), 0, stream,
                       x, feat, hidx, (float4*)d_out, sp, N);
}